// Round 1
// baseline (1619.791 us; speedup 1.0000x reference)
//
#include <hip/hip_runtime.h>

#define NPART 22
#define NDEG  21          // out-degree per node
#define NEDGE 462         // 22*21 ordered pairs
#define HID   64
#define NLAYERS 4
#define ET    32          // edge tile
#define TS    34          // padded tile row stride (floats)

__device__ __forceinline__ float silu_f(float v) {
    return v / (1.0f + __expf(-v));
}

__global__ __launch_bounds__(256, 2)
void egnn_fused(const float* __restrict__ t_in,
                const float* __restrict__ xs,
                const float* __restrict__ h_init,
                const float* __restrict__ emb_w,
                const float* __restrict__ emb_b,
                const float* __restrict__ edge_w1,
                const float* __restrict__ edge_b1,
                const float* __restrict__ edge_w2,
                const float* __restrict__ edge_b2,
                const float* __restrict__ node_w1,
                const float* __restrict__ node_b1,
                const float* __restrict__ node_w2,
                const float* __restrict__ node_b2,
                const float* __restrict__ coord_w1,
                const float* __restrict__ coord_b1,
                const float* __restrict__ coord_w2,
                float* __restrict__ out)
{
    __shared__ float W0 [HID][HID];     // weight stage 0 (16 KB)
    __shared__ float W1s[HID][HID];     // weight stage 1 (16 KB)
    __shared__ float hsh[NPART][HID];
    __shared__ float Hr [NPART][HID];
    __shared__ float Hc [NPART][HID];
    __shared__ float aggs[NPART][HID];
    __shared__ float m1T[HID][TS];      // transposed m1 tile [k][e]
    __shared__ float mT [HID][TS];      // transposed m  tile [k][e]
    __shared__ float eas[NEDGE];
    __shared__ float xl [NPART][3];
    __shared__ float x0l[NPART][3];
    __shared__ float dxl[NPART][3];
    __shared__ float vrad[HID], vea[HID], vb1[HID], vb2[HID];
    __shared__ float vcb1[HID], vcw2[HID], vbn1[HID], vbn2[HID];
    __shared__ float radial_s[ET];
    __shared__ float dif_s[ET][3];
    __shared__ float scal_s[ET];
    __shared__ float meanv[3];

    const int b   = blockIdx.x;
    const int tid = threadIdx.x;
    const float tb = t_in[b];

    // ---- init: coords, embedding, agg=0 ----
    {
        float* x0f = &x0l[0][0];
        float* xf  = &xl[0][0];
        float* dxf = &dxl[0][0];
        for (int i = tid; i < NPART*3; i += 256) {
            float v = xs[b*(NPART*3) + i];
            x0f[i] = v; xf[i] = v; dxf[i] = 0.f;
        }
    }
    for (int idx = tid; idx < NPART*HID; idx += 256) {
        int n = idx >> 6, j = idx & 63;
        float acc = emb_b[j] + tb * emb_w[8*HID + j];
        #pragma unroll
        for (int k = 0; k < 8; ++k) acc += h_init[n*8 + k] * emb_w[k*HID + j];
        hsh[n][j] = acc;
        aggs[n][j] = 0.f;
    }
    __syncthreads();
    // static edge attr (squared distance at x0)
    for (int e = tid; e < NEDGE; e += 256) {
        int a = e / NDEG, r = e - a*NDEG;
        int bb = r + (r >= a ? 1 : 0);
        float d0 = x0l[a][0]-x0l[bb][0];
        float d1 = x0l[a][1]-x0l[bb][1];
        float d2 = x0l[a][2]-x0l[bb][2];
        eas[e] = d0*d0 + d1*d1 + d2*d2;
    }
    __syncthreads();

    for (int L = 0; L < NLAYERS; ++L) {
        // ---- stage edge_w1 halves + small vectors ----
        const float* w1 = edge_w1 + L*130*HID;
        for (int idx = tid; idx < HID*HID; idx += 256) {
            W0 [idx>>6][idx&63] = w1[idx];
            W1s[idx>>6][idx&63] = w1[64*HID + idx];
        }
        if (tid < HID) {
            vrad[tid] = w1[128*HID + tid];
            vea [tid] = w1[129*HID + tid];
            vb1 [tid] = edge_b1[L*HID + tid];
            vb2 [tid] = edge_b2[L*HID + tid];
            vcb1[tid] = coord_b1[L*HID + tid];
            vcw2[tid] = coord_w2[L*HID + tid];
            vbn1[tid] = node_b1[L*HID + tid];
            vbn2[tid] = node_b2[L*HID + tid];
        }
        __syncthreads();
        // ---- Hr = h @ W1r ; Hc = h @ W1c ----
        for (int idx = tid; idx < NPART*HID; idx += 256) {
            int n = idx >> 6, j = idx & 63;
            float ar = 0.f, ac = 0.f;
            #pragma unroll 8
            for (int k = 0; k < HID; ++k) {
                float hv = hsh[n][k];
                ar += hv * W0[k][j];
                ac += hv * W1s[k][j];
            }
            Hr[n][j] = ar;
            Hc[n][j] = ac;
        }
        __syncthreads();
        // ---- stage edge_w2 -> W0, coord_w1 -> W1s ----
        for (int idx = tid; idx < HID*HID; idx += 256) {
            W0 [idx>>6][idx&63] = edge_w2 [L*HID*HID + idx];
            W1s[idx>>6][idx&63] = coord_w1[L*HID*HID + idx];
        }
        __syncthreads();

        // ---- edge tiles ----
        for (int t0 = 0; t0 < NEDGE; t0 += ET) {
            const int ecnt = (NEDGE - t0 < ET) ? (NEDGE - t0) : ET;
            // per-edge geometry
            if (tid < ecnt) {
                int eg = t0 + tid;
                int a = eg / NDEG, r = eg - a*NDEG;
                int bb = r + (r >= a ? 1 : 0);
                float d0 = xl[a][0]-xl[bb][0];
                float d1 = xl[a][1]-xl[bb][1];
                float d2 = xl[a][2]-xl[bb][2];
                float rad = d0*d0 + d1*d1 + d2*d2;
                radial_s[tid] = rad;
                float inv = 1.0f / sqrtf(rad + 1e-8f);
                dif_s[tid][0] = d0*inv;
                dif_s[tid][1] = d1*inv;
                dif_s[tid][2] = d2*inv;
            }
            __syncthreads();
            // ---- m1 = silu(Hr[a]+Hc[b]+rad*wrad+ea*wea+b1), transposed store ----
            {
                const int k  = tid & 63;
                const int e0 = (tid >> 6) * 8;
                #pragma unroll
                for (int i = 0; i < 8; ++i) {
                    int e = e0 + i;
                    if (e < ecnt) {
                        int eg = t0 + e;
                        int a = eg / NDEG, r = eg - a*NDEG;
                        int bb = r + (r >= a ? 1 : 0);
                        float v = Hr[a][k] + Hc[bb][k]
                                + radial_s[e]*vrad[k] + eas[eg]*vea[k] + vb1[k];
                        m1T[k][e] = silu_f(v);
                    } else {
                        m1T[k][e] = 0.f;
                    }
                }
            }
            __syncthreads();
            // ---- m = silu(m1 @ W2 + b2): write mT, accumulate agg ----
            {
                const int jb = (tid & 15) << 2;
                const int eb = (tid >> 4) << 1;
                float acc[2][4] = {{0,0,0,0},{0,0,0,0}};
                #pragma unroll 4
                for (int k = 0; k < HID; ++k) {
                    float2 av = *(const float2*)&m1T[k][eb];
                    float4 wv = *(const float4*)&W0[k][jb];
                    acc[0][0] += av.x*wv.x; acc[0][1] += av.x*wv.y;
                    acc[0][2] += av.x*wv.z; acc[0][3] += av.x*wv.w;
                    acc[1][0] += av.y*wv.x; acc[1][1] += av.y*wv.y;
                    acc[1][2] += av.y*wv.z; acc[1][3] += av.y*wv.w;
                }
                #pragma unroll
                for (int i = 0; i < 2; ++i) {
                    int e = eb + i;
                    if (e < ecnt) {
                        int eg = t0 + e;
                        int a = eg / NDEG;
                        #pragma unroll
                        for (int l = 0; l < 4; ++l) {
                            float mv = silu_f(acc[i][l] + vb2[jb+l]);
                            mT[jb+l][e] = mv;
                            atomicAdd(&aggs[a][jb+l], mv);
                        }
                    }
                }
            }
            __syncthreads();
            // ---- c1 = silu(m @ Wc1 + cb1); scal = c1 @ cw2 (reduce over 16 lanes) ----
            {
                const int jb = (tid & 15) << 2;
                const int eb = (tid >> 4) << 1;
                float acc[2][4] = {{0,0,0,0},{0,0,0,0}};
                #pragma unroll 4
                for (int k = 0; k < HID; ++k) {
                    float2 av = *(const float2*)&mT[k][eb];
                    float4 wv = *(const float4*)&W1s[k][jb];
                    acc[0][0] += av.x*wv.x; acc[0][1] += av.x*wv.y;
                    acc[0][2] += av.x*wv.z; acc[0][3] += av.x*wv.w;
                    acc[1][0] += av.y*wv.x; acc[1][1] += av.y*wv.y;
                    acc[1][2] += av.y*wv.z; acc[1][3] += av.y*wv.w;
                }
                float p0 = 0.f, p1 = 0.f;
                #pragma unroll
                for (int l = 0; l < 4; ++l) {
                    p0 += silu_f(acc[0][l] + vcb1[jb+l]) * vcw2[jb+l];
                    p1 += silu_f(acc[1][l] + vcb1[jb+l]) * vcw2[jb+l];
                }
                p0 += __shfl_down(p0, 8, 16); p1 += __shfl_down(p1, 8, 16);
                p0 += __shfl_down(p0, 4, 16); p1 += __shfl_down(p1, 4, 16);
                p0 += __shfl_down(p0, 2, 16); p1 += __shfl_down(p1, 2, 16);
                p0 += __shfl_down(p0, 1, 16); p1 += __shfl_down(p1, 1, 16);
                if ((tid & 15) == 0) {
                    scal_s[eb]   = p0;
                    scal_s[eb+1] = p1;
                }
            }
            __syncthreads();
            // ---- coordinate update accumulation ----
            if (tid < ecnt) {
                int eg = t0 + tid;
                int a = eg / NDEG;
                float s = scal_s[tid];
                atomicAdd(&dxl[a][0], dif_s[tid][0]*s);
                atomicAdd(&dxl[a][1], dif_s[tid][1]*s);
                atomicAdd(&dxl[a][2], dif_s[tid][2]*s);
            }
            __syncthreads();
        }

        // ---- node MLP: hn = silu([h,agg] @ Wn1 + bn1); h += hn @ Wn2 + bn2 ----
        for (int idx = tid; idx < HID*HID; idx += 256) {
            W0 [idx>>6][idx&63] = node_w1[L*128*HID + idx];
            W1s[idx>>6][idx&63] = node_w1[L*128*HID + 64*HID + idx];
        }
        __syncthreads();
        float* hn = &m1T[0][0];   // reuse tile buffer
        for (int idx = tid; idx < NPART*HID; idx += 256) {
            int n = idx >> 6, j = idx & 63;
            float acc = vbn1[j];
            #pragma unroll 8
            for (int k = 0; k < HID; ++k)
                acc += hsh[n][k]*W0[k][j] + aggs[n][k]*W1s[k][j];
            hn[idx] = silu_f(acc);
        }
        __syncthreads();
        for (int idx = tid; idx < HID*HID; idx += 256)
            W0[idx>>6][idx&63] = node_w2[L*HID*HID + idx];
        __syncthreads();
        for (int idx = tid; idx < NPART*HID; idx += 256) {
            int n = idx >> 6, j = idx & 63;
            float acc = vbn2[j];
            #pragma unroll 8
            for (int k = 0; k < HID; ++k) acc += hn[n*HID + k]*W0[k][j];
            hsh[n][j] += acc;
            aggs[n][j] = 0.f;    // reset for next layer
        }
        // ---- apply coordinate update ----
        if (tid < NPART*3) {
            int n = tid / 3, d = tid - n*3;
            xl[n][d] += dxl[n][d];
            dxl[n][d] = 0.f;
        }
        __syncthreads();
    }

    // ---- vel = (x - x0) minus per-batch mean over particles ----
    if (tid < 3) {
        float s = 0.f;
        #pragma unroll
        for (int n = 0; n < NPART; ++n) s += xl[n][tid] - x0l[n][tid];
        meanv[tid] = s / (float)NPART;
    }
    __syncthreads();
    if (tid < NPART*3) {
        int n = tid / 3, d = tid - n*3;
        out[b*(NPART*3) + tid] = (xl[n][d] - x0l[n][d]) - meanv[d];
    }
}

extern "C" void kernel_launch(void* const* d_in, const int* in_sizes, int n_in,
                              void* d_out, int out_size, void* d_ws, size_t ws_size,
                              hipStream_t stream) {
    const float* t_in     = (const float*)d_in[0];
    const float* xs       = (const float*)d_in[1];
    const float* h_init   = (const float*)d_in[2];
    const float* emb_w    = (const float*)d_in[3];
    const float* emb_b    = (const float*)d_in[4];
    // d_in[5], d_in[6]: emb_out_w / emb_out_b — unused by the output
    const float* edge_w1  = (const float*)d_in[7];
    const float* edge_b1  = (const float*)d_in[8];
    const float* edge_w2  = (const float*)d_in[9];
    const float* edge_b2  = (const float*)d_in[10];
    const float* node_w1  = (const float*)d_in[11];
    const float* node_b1  = (const float*)d_in[12];
    const float* node_w2  = (const float*)d_in[13];
    const float* node_b2  = (const float*)d_in[14];
    const float* coord_w1 = (const float*)d_in[15];
    const float* coord_b1 = (const float*)d_in[16];
    const float* coord_w2 = (const float*)d_in[17];
    float* outp = (float*)d_out;

    const int Bn = in_sizes[0];   // t is (B,1)
    egnn_fused<<<Bn, 256, 0, stream>>>(
        t_in, xs, h_init, emb_w, emb_b,
        edge_w1, edge_b1, edge_w2, edge_b2,
        node_w1, node_b1, node_w2, node_b2,
        coord_w1, coord_b1, coord_w2, outp);
}

// Round 2
// 1160.784 us; speedup vs baseline: 1.3954x; 1.3954x over previous
//
#include <hip/hip_runtime.h>

#define NPART 22
#define NDEG  21
#define NEDGE 462
#define HID   64
#define NLAYERS 4
#define ET    32

typedef __attribute__((ext_vector_type(8))) short bf16x8;
typedef __attribute__((ext_vector_type(4))) float f32x4;
typedef __attribute__((ext_vector_type(4))) unsigned int u32x4;

__device__ __forceinline__ float silu_f(float v) {
    return v / (1.0f + __expf(-v));
}
// round-to-nearest-even f32 -> bf16 (as u16 in low bits)
__device__ __forceinline__ unsigned f2bf(float x) {
    unsigned u = __float_as_uint(x);
    return (u + 0x7FFFu + ((u >> 16) & 1u)) >> 16;
}
__device__ __forceinline__ float bf2f(unsigned h) {
    return __uint_as_float(h << 16);
}

// Stage a 64x64 f32 row-major [k][j] global matrix into LDS as TRANSPOSED
// bf16 hi/lo: layout [h][j][k], h-stride 8192 B, row stride 128 B,
// byte-in-row swizzle: (k*2) ^ ((j&7)<<4).
__device__ __forceinline__ void stage_wt_bf16(const float* __restrict__ Wg,
                                              char* dst, int tid) {
    const int j  = tid & 63;
    const int kb = tid >> 6;          // 0..3 -> 16 k each
    u32x4 h0v, h1v, l0v, l1v;
    #pragma unroll
    for (int i = 0; i < 16; i += 2) {
        float v0 = Wg[(kb * 16 + i) * 64 + j];
        float v1 = Wg[(kb * 16 + i + 1) * 64 + j];
        unsigned hh0 = f2bf(v0), hh1 = f2bf(v1);
        unsigned ll0 = f2bf(v0 - bf2f(hh0)), ll1 = f2bf(v1 - bf2f(hh1));
        unsigned hp = hh0 | (hh1 << 16);
        unsigned lp = ll0 | (ll1 << 16);
        int q = i >> 1;               // 0..7
        if (q < 4) { h0v[q] = hp; l0v[q] = lp; }
        else       { h1v[q - 4] = hp; l1v[q - 4] = lp; }
    }
    const int swz = (j & 7) << 4;
    char* rowp = dst + j * 128;
    *(u32x4*)(rowp + ((kb * 32)      ^ swz)) = h0v;
    *(u32x4*)(rowp + ((kb * 32 + 16) ^ swz)) = h1v;
    *(u32x4*)(rowp + 8192 + ((kb * 32)      ^ swz)) = l0v;
    *(u32x4*)(rowp + 8192 + ((kb * 32 + 16) ^ swz)) = l1v;
}

// Per-wave: compute 2 output tiles (16x16 each) of  out = A[32x64] @ W[64x64]
// A: bf16 hi/lo at abuf, layout [h][e][k], h-stride 4096, row 128 B, swizzled.
// W: bf16 hi/lo transposed at wbuf (see stage_wt_bf16).
// Split product: Ah@Wh + Ah@Wl + Al@Wh  (~fp32 accuracy).
__device__ __forceinline__ void mfma_tile2(const char* abuf, const char* wbuf,
                                           int mt, int nt0, int l,
                                           f32x4& acc0, f32x4& acc1) {
    const int arow = mt * 16 + (l & 15);
    const int kg   = l >> 4;
    const int asw  = (arow & 7) << 4;
    const char* ar = abuf + arow * 128;
    bf16x8 Ah0 = *(const bf16x8*)(ar + ((kg * 16) ^ asw));
    bf16x8 Ah1 = *(const bf16x8*)(ar + ((64 + kg * 16) ^ asw));
    bf16x8 Al0 = *(const bf16x8*)(ar + 4096 + ((kg * 16) ^ asw));
    bf16x8 Al1 = *(const bf16x8*)(ar + 4096 + ((64 + kg * 16) ^ asw));

    const int j0 = nt0 * 16 + (l & 15);
    const int sw = (j0 & 7) << 4;     // j0+16 keeps the same low 3 bits
    const char* r0 = wbuf + j0 * 128;
    const char* r1 = wbuf + (j0 + 16) * 128;
    bf16x8 B0h0 = *(const bf16x8*)(r0 + ((kg * 16) ^ sw));
    bf16x8 B0h1 = *(const bf16x8*)(r0 + ((64 + kg * 16) ^ sw));
    bf16x8 B0l0 = *(const bf16x8*)(r0 + 8192 + ((kg * 16) ^ sw));
    bf16x8 B0l1 = *(const bf16x8*)(r0 + 8192 + ((64 + kg * 16) ^ sw));
    bf16x8 B1h0 = *(const bf16x8*)(r1 + ((kg * 16) ^ sw));
    bf16x8 B1h1 = *(const bf16x8*)(r1 + ((64 + kg * 16) ^ sw));
    bf16x8 B1l0 = *(const bf16x8*)(r1 + 8192 + ((kg * 16) ^ sw));
    bf16x8 B1l1 = *(const bf16x8*)(r1 + 8192 + ((64 + kg * 16) ^ sw));

    acc0 = __builtin_amdgcn_mfma_f32_16x16x32_bf16(Ah0, B0h0, acc0, 0, 0, 0);
    acc0 = __builtin_amdgcn_mfma_f32_16x16x32_bf16(Ah1, B0h1, acc0, 0, 0, 0);
    acc0 = __builtin_amdgcn_mfma_f32_16x16x32_bf16(Ah0, B0l0, acc0, 0, 0, 0);
    acc0 = __builtin_amdgcn_mfma_f32_16x16x32_bf16(Ah1, B0l1, acc0, 0, 0, 0);
    acc0 = __builtin_amdgcn_mfma_f32_16x16x32_bf16(Al0, B0h0, acc0, 0, 0, 0);
    acc0 = __builtin_amdgcn_mfma_f32_16x16x32_bf16(Al1, B0h1, acc0, 0, 0, 0);

    acc1 = __builtin_amdgcn_mfma_f32_16x16x32_bf16(Ah0, B1h0, acc1, 0, 0, 0);
    acc1 = __builtin_amdgcn_mfma_f32_16x16x32_bf16(Ah1, B1h1, acc1, 0, 0, 0);
    acc1 = __builtin_amdgcn_mfma_f32_16x16x32_bf16(Ah0, B1l0, acc1, 0, 0, 0);
    acc1 = __builtin_amdgcn_mfma_f32_16x16x32_bf16(Ah1, B1l1, acc1, 0, 0, 0);
    acc1 = __builtin_amdgcn_mfma_f32_16x16x32_bf16(Al0, B1h0, acc1, 0, 0, 0);
    acc1 = __builtin_amdgcn_mfma_f32_16x16x32_bf16(Al1, B1h1, acc1, 0, 0, 0);
}

__global__ __launch_bounds__(256, 2)
void egnn_fused(const float* __restrict__ t_in,
                const float* __restrict__ xs,
                const float* __restrict__ h_init,
                const float* __restrict__ emb_w,
                const float* __restrict__ emb_b,
                const float* __restrict__ edge_w1,
                const float* __restrict__ edge_b1,
                const float* __restrict__ edge_w2,
                const float* __restrict__ edge_b2,
                const float* __restrict__ node_w1,
                const float* __restrict__ node_b1,
                const float* __restrict__ node_w2,
                const float* __restrict__ node_b2,
                const float* __restrict__ coord_w1,
                const float* __restrict__ coord_b1,
                const float* __restrict__ coord_w2,
                float* __restrict__ out)
{
    // raw region: [0,32K) f32 weight scratch WSf (or 2x bf16 matrices)
    //             [32K,40K) m1 bf16 hi/lo tile   [40K,48K) m bf16 hi/lo tile
    __shared__ __align__(16) char sraw[49152];
    __shared__ float hsh[NPART][HID];
    __shared__ float Hr [NPART][HID];
    __shared__ float Hc [NPART][HID];
    __shared__ float aggs[NPART][HID];
    __shared__ float eas[NEDGE];
    __shared__ float xl [NPART][3], x0l[NPART][3], dxl[NPART][3];
    __shared__ float vrad[HID], vea[HID], vb1[HID], vb2[HID];
    __shared__ float vcb1[HID], vcw2[HID], vbn1[HID], vbn2[HID];
    __shared__ float dif_s[ET][3], scal_s[ET];
    __shared__ int   srcA_s[ET];
    __shared__ float meanv[3];

    float* WSf = (float*)sraw;
    char*  m1b = sraw + 32768;
    char*  mb  = sraw + 40960;

    const int b   = blockIdx.x;
    const int tid = threadIdx.x;
    const int l   = tid & 63;
    const int w   = tid >> 6;
    const float tb = t_in[b];

    // ---- init: coords, embedding, agg=0 ----
    {
        float* x0f = &x0l[0][0];
        float* xf  = &xl[0][0];
        float* dxf = &dxl[0][0];
        for (int i = tid; i < NPART * 3; i += 256) {
            float v = xs[b * (NPART * 3) + i];
            x0f[i] = v; xf[i] = v; dxf[i] = 0.f;
        }
    }
    for (int idx = tid; idx < NPART * HID; idx += 256) {
        int n = idx >> 6, j = idx & 63;
        float acc = emb_b[j] + tb * emb_w[8 * HID + j];
        #pragma unroll
        for (int k = 0; k < 8; ++k) acc += h_init[n * 8 + k] * emb_w[k * HID + j];
        hsh[n][j] = acc;
        aggs[n][j] = 0.f;
    }
    __syncthreads();
    for (int e = tid; e < NEDGE; e += 256) {
        int a = e / NDEG, r = e - a * NDEG;
        int bb = r + (r >= a ? 1 : 0);
        float d0 = x0l[a][0] - x0l[bb][0];
        float d1 = x0l[a][1] - x0l[bb][1];
        float d2 = x0l[a][2] - x0l[bb][2];
        eas[e] = d0 * d0 + d1 * d1 + d2 * d2;
    }
    __syncthreads();

    for (int L = 0; L < NLAYERS; ++L) {
        // ---- stage edge_w1 (both 64-row halves) f32 + per-layer vectors ----
        const float* w1 = edge_w1 + L * 130 * HID;
        for (int idx = tid; idx < 2 * HID * HID; idx += 256) WSf[idx] = w1[idx];
        if (tid < HID) {
            vrad[tid] = w1[128 * HID + tid];
            vea [tid] = w1[129 * HID + tid];
            vb1 [tid] = edge_b1[L * HID + tid];
            vb2 [tid] = edge_b2[L * HID + tid];
            vcb1[tid] = coord_b1[L * HID + tid];
            vcw2[tid] = coord_w2[L * HID + tid];
            vbn1[tid] = node_b1[L * HID + tid];
            vbn2[tid] = node_b2[L * HID + tid];
        }
        __syncthreads();
        // ---- Hr = h @ W1r ; Hc = h @ W1c  (f32 VALU, small) ----
        for (int idx = tid; idx < NPART * HID; idx += 256) {
            int n = idx >> 6, j = idx & 63;
            float ar = 0.f, ac = 0.f;
            #pragma unroll 8
            for (int k = 0; k < HID; ++k) {
                float hv = hsh[n][k];
                ar += hv * WSf[k * 64 + j];
                ac += hv * WSf[4096 + k * 64 + j];
            }
            Hr[n][j] = ar;
            Hc[n][j] = ac;
        }
        __syncthreads();
        // ---- stage W2, Wc1 as transposed split-bf16 (overwrites WSf) ----
        stage_wt_bf16(edge_w2  + L * HID * HID, sraw,         tid);
        stage_wt_bf16(coord_w1 + L * HID * HID, sraw + 16384, tid);
        __syncthreads();

        // ---- edge tiles ----
        for (int t0 = 0; t0 < NEDGE; t0 += ET) {
            const int ecnt = (NEDGE - t0 < ET) ? (NEDGE - t0) : ET;

            // phase AB: geometry + m1 (f32 -> split bf16, swizzled A layout)
            {
                const int e  = tid >> 3;
                const int ks = (tid & 7) << 3;
                int eg = t0 + e; if (eg >= NEDGE) eg = NEDGE - 1;
                int a = eg / NDEG, rr = eg - a * NDEG;
                int bb = rr + (rr >= a ? 1 : 0);
                float d0 = xl[a][0] - xl[bb][0];
                float d1 = xl[a][1] - xl[bb][1];
                float d2 = xl[a][2] - xl[bb][2];
                float rad = d0 * d0 + d1 * d1 + d2 * d2;
                float ea = eas[eg];
                if ((tid & 7) == 0) {
                    srcA_s[e] = a;
                    float inv = 1.0f / sqrtf(rad + 1e-8f);
                    dif_s[e][0] = d0 * inv;
                    dif_s[e][1] = d1 * inv;
                    dif_s[e][2] = d2 * inv;
                    scal_s[e] = 0.f;
                }
                u32x4 hv, lv;
                #pragma unroll
                for (int i = 0; i < 8; i += 2) {
                    int k = ks + i;
                    float v0 = silu_f(Hr[a][k]     + Hc[bb][k]     + rad * vrad[k]     + ea * vea[k]     + vb1[k]);
                    float v1 = silu_f(Hr[a][k + 1] + Hc[bb][k + 1] + rad * vrad[k + 1] + ea * vea[k + 1] + vb1[k + 1]);
                    unsigned h0 = f2bf(v0), h1 = f2bf(v1);
                    unsigned q0 = f2bf(v0 - bf2f(h0)), q1 = f2bf(v1 - bf2f(h1));
                    hv[i >> 1] = h0 | (h1 << 16);
                    lv[i >> 1] = q0 | (q1 << 16);
                }
                int boff = e * 128 + ((ks * 2) ^ ((e & 7) << 4));
                *(u32x4*)(m1b + boff) = hv;
                *(u32x4*)(m1b + 4096 + boff) = lv;
            }
            __syncthreads();

            // phase C: m = silu(m1 @ W2 + b2) via MFMA; agg (f32) + m bf16 store
            {
                const int mt  = w & 1;
                const int nt0 = (w >> 1) << 1;
                f32x4 a0 = {0.f, 0.f, 0.f, 0.f}, a1 = {0.f, 0.f, 0.f, 0.f};
                mfma_tile2(m1b, sraw, mt, nt0, l, a0, a1);
                const int kg = l >> 4;
                #pragma unroll
                for (int nt = 0; nt < 2; ++nt) {
                    f32x4 ac = nt ? a1 : a0;
                    int j = (nt0 + nt) * 16 + (l & 15);
                    #pragma unroll
                    for (int r = 0; r < 4; ++r) {
                        int e = mt * 16 + kg * 4 + r;
                        float mv = silu_f(ac[r] + vb2[j]);
                        unsigned hh = f2bf(mv);
                        unsigned ll = f2bf(mv - bf2f(hh));
                        int boff = e * 128 + ((j * 2) ^ ((e & 7) << 4));
                        *(short*)(mb + boff) = (short)hh;
                        *(short*)(mb + 4096 + boff) = (short)ll;
                        if (e < ecnt) atomicAdd(&aggs[srcA_s[e]][j], mv);
                    }
                }
            }
            __syncthreads();

            // phase D: c1 = silu(m @ Wc1 + cb1); scal = c1 @ cw2 (row-reduce)
            {
                const int mt  = w & 1;
                const int nt0 = (w >> 1) << 1;
                f32x4 a0 = {0.f, 0.f, 0.f, 0.f}, a1 = {0.f, 0.f, 0.f, 0.f};
                mfma_tile2(mb, sraw + 16384, mt, nt0, l, a0, a1);
                const int kg = l >> 4;
                float sr[4];
                #pragma unroll
                for (int r = 0; r < 4; ++r) {
                    int j0 = nt0 * 16 + (l & 15);
                    int j1 = j0 + 16;
                    sr[r] = silu_f(a0[r] + vcb1[j0]) * vcw2[j0]
                          + silu_f(a1[r] + vcb1[j1]) * vcw2[j1];
                }
                #pragma unroll
                for (int off = 8; off > 0; off >>= 1) {
                    #pragma unroll
                    for (int r = 0; r < 4; ++r)
                        sr[r] += __shfl_xor(sr[r], off, 16);
                }
                if ((l & 15) == 0) {
                    #pragma unroll
                    for (int r = 0; r < 4; ++r) {
                        int e = mt * 16 + kg * 4 + r;
                        if (e < ecnt) atomicAdd(&scal_s[e], sr[r]);
                    }
                }
            }
            __syncthreads();

            // phase E: coordinate update accumulation
            if (tid < ecnt) {
                int a = srcA_s[tid];
                float s = scal_s[tid];
                atomicAdd(&dxl[a][0], dif_s[tid][0] * s);
                atomicAdd(&dxl[a][1], dif_s[tid][1] * s);
                atomicAdd(&dxl[a][2], dif_s[tid][2] * s);
            }
            __syncthreads();
        }

        // ---- node MLP ----
        for (int idx = tid; idx < 2 * HID * HID; idx += 256)
            WSf[idx] = node_w1[L * 2 * HID * HID + idx];
        __syncthreads();
        float* hnf = (float*)m1b;   // reuse bf16 tile region as f32 scratch
        for (int idx = tid; idx < NPART * HID; idx += 256) {
            int n = idx >> 6, j = idx & 63;
            float acc = vbn1[j];
            #pragma unroll 8
            for (int k = 0; k < HID; ++k)
                acc += hsh[n][k] * WSf[k * 64 + j] + aggs[n][k] * WSf[(64 + k) * 64 + j];
            hnf[idx] = silu_f(acc);
        }
        __syncthreads();
        for (int idx = tid; idx < HID * HID; idx += 256)
            WSf[idx] = node_w2[L * HID * HID + idx];
        __syncthreads();
        for (int idx = tid; idx < NPART * HID; idx += 256) {
            int n = idx >> 6, j = idx & 63;
            float acc = vbn2[j];
            #pragma unroll 8
            for (int k = 0; k < HID; ++k) acc += hnf[n * HID + k] * WSf[k * 64 + j];
            hsh[n][j] += acc;
            aggs[n][j] = 0.f;
        }
        if (tid < NPART * 3) {
            int n = tid / 3, d = tid - n * 3;
            xl[n][d] += dxl[n][d];
            dxl[n][d] = 0.f;
        }
        __syncthreads();
    }

    // ---- vel = (x - x0) minus per-batch mean over particles ----
    if (tid < 3) {
        float s = 0.f;
        #pragma unroll
        for (int n = 0; n < NPART; ++n) s += xl[n][tid] - x0l[n][tid];
        meanv[tid] = s / (float)NPART;
    }
    __syncthreads();
    if (tid < NPART * 3) {
        int n = tid / 3, d = tid - n * 3;
        out[b * (NPART * 3) + tid] = (xl[n][d] - x0l[n][d]) - meanv[d];
    }
}

extern "C" void kernel_launch(void* const* d_in, const int* in_sizes, int n_in,
                              void* d_out, int out_size, void* d_ws, size_t ws_size,
                              hipStream_t stream) {
    const float* t_in     = (const float*)d_in[0];
    const float* xs       = (const float*)d_in[1];
    const float* h_init   = (const float*)d_in[2];
    const float* emb_w    = (const float*)d_in[3];
    const float* emb_b    = (const float*)d_in[4];
    const float* edge_w1  = (const float*)d_in[7];
    const float* edge_b1  = (const float*)d_in[8];
    const float* edge_w2  = (const float*)d_in[9];
    const float* edge_b2  = (const float*)d_in[10];
    const float* node_w1  = (const float*)d_in[11];
    const float* node_b1  = (const float*)d_in[12];
    const float* node_w2  = (const float*)d_in[13];
    const float* node_b2  = (const float*)d_in[14];
    const float* coord_w1 = (const float*)d_in[15];
    const float* coord_b1 = (const float*)d_in[16];
    const float* coord_w2 = (const float*)d_in[17];
    float* outp = (float*)d_out;

    const int Bn = in_sizes[0];
    egnn_fused<<<Bn, 256, 0, stream>>>(
        t_in, xs, h_init, emb_w, emb_b,
        edge_w1, edge_b1, edge_w2, edge_b2,
        node_w1, node_b1, node_w2, node_b2,
        coord_w1, coord_b1, coord_w2, outp);
}

// Round 3
// 1101.311 us; speedup vs baseline: 1.4708x; 1.0540x over previous
//
#include <hip/hip_runtime.h>

#define NPART 22
#define NDEG  21
#define NEDGE 462
#define HID   64
#define NLAYERS 4
#define NSTRIP 29
#define NS    68     // padded row stride (floats) for node-indexed arrays

typedef __attribute__((ext_vector_type(8))) short bf16x8;
typedef __attribute__((ext_vector_type(4))) float f32x4;
typedef __attribute__((ext_vector_type(4))) unsigned int u32x4;

__device__ __forceinline__ float silu_f(float v) {
    return __fdividef(v, 1.0f + __expf(-v));
}
__device__ __forceinline__ unsigned f2bf(float x) {
    unsigned u = __float_as_uint(x);
    return (u + 0x7FFFu + ((u >> 16) & 1u)) >> 16;
}
__device__ __forceinline__ float bf2f(unsigned h) { return __uint_as_float(h << 16); }

// split 8 f32 (two float4, consecutive k) into hi/lo bf16x8 fragments
__device__ __forceinline__ void split8(float4 a, float4 b, bf16x8& hi, bf16x8& lo) {
    u32x4 ph, pl;
    float va[8] = {a.x, a.y, a.z, a.w, b.x, b.y, b.z, b.w};
    #pragma unroll
    for (int i = 0; i < 4; ++i) {
        float v0 = va[2*i], v1 = va[2*i+1];
        unsigned h0 = f2bf(v0), h1 = f2bf(v1);
        unsigned l0 = f2bf(v0 - bf2f(h0)), l1 = f2bf(v1 - bf2f(h1));
        ph[i] = h0 | (h1 << 16);
        pl[i] = l0 | (l1 << 16);
    }
    hi = __builtin_bit_cast(bf16x8, ph);
    lo = __builtin_bit_cast(bf16x8, pl);
}

// Stage 64x64 f32 row-major [k][j] -> LDS transposed single bf16 [j][k],
// row 128 B, swizzle: byte_k ^ ((j&7)<<4).
__device__ __forceinline__ void stage_wt_bf16s(const float* __restrict__ Wg,
                                               char* dst, int tid) {
    const int j  = tid & 63;
    const int kb = tid >> 6;     // 0..3 -> 16 k each
    u32x4 p0, p1;
    #pragma unroll
    for (int i = 0; i < 8; i += 2) {
        float v0 = Wg[(kb*16 + i) * 64 + j];
        float v1 = Wg[(kb*16 + i + 1) * 64 + j];
        p0[i >> 1] = f2bf(v0) | (f2bf(v1) << 16);
    }
    #pragma unroll
    for (int i = 8; i < 16; i += 2) {
        float v0 = Wg[(kb*16 + i) * 64 + j];
        float v1 = Wg[(kb*16 + i + 1) * 64 + j];
        p1[(i - 8) >> 1] = f2bf(v0) | (f2bf(v1) << 16);
    }
    const int swz = (j & 7) << 4;
    char* rowp = dst + j * 128;
    *(u32x4*)(rowp + ((kb*32)      ^ swz)) = p0;
    *(u32x4*)(rowp + ((kb*32 + 16) ^ swz)) = p1;
}

__global__ __launch_bounds__(256, 2)
void egnn_fused(const float* __restrict__ t_in,
                const float* __restrict__ xs,
                const float* __restrict__ h_init,
                const float* __restrict__ emb_w,
                const float* __restrict__ emb_b,
                const float* __restrict__ edge_w1,
                const float* __restrict__ edge_b1,
                const float* __restrict__ edge_w2,
                const float* __restrict__ edge_b2,
                const float* __restrict__ node_w1,
                const float* __restrict__ node_b1,
                const float* __restrict__ node_w2,
                const float* __restrict__ node_b2,
                const float* __restrict__ coord_w1,
                const float* __restrict__ coord_b1,
                const float* __restrict__ coord_w2,
                float* __restrict__ out)
{
    // wbuf: edge phase = W2t bf16 [0,8K) + Wc1t bf16 [8K,16K); node phase = node_w1 f32 (32K)
    __shared__ __align__(16) char  wbuf[32768];
    __shared__ __align__(16) float mwav[4 * 16 * NS];   // wave-private m tiles; node_w2 staging
    __shared__ __align__(16) float hsh [NPART][NS];
    __shared__ __align__(16) float Hr  [NPART][NS];     // also hn scratch in node phase
    __shared__ __align__(16) float Hc  [NPART][NS];
    __shared__ __align__(16) float aggs[NPART][NS];
    __shared__ float vrad[HID], vea[HID], vb2[HID];
    __shared__ float vcb1[HID], vcw2[HID], vbn1[HID], vbn2[HID];
    __shared__ float xl[NPART][3], x0l[NPART][3], dxl[NPART][3];
    __shared__ float scal_sw[4][16];
    __shared__ unsigned char srcT[464], dstT[464];
    __shared__ float meanv[3];

    const int b   = blockIdx.x;
    const int tid = threadIdx.x;
    const int l   = tid & 63;
    const int w   = tid >> 6;
    const int kg  = l >> 4;
    const int j0  = l & 15;
    const float tb = t_in[b];
    float* aggsF = &aggs[0][0];
    float* mw    = mwav + w * 16 * NS;

    // ---- init ----
    {
        float* x0f = &x0l[0][0];
        float* xf  = &xl[0][0];
        float* dxf = &dxl[0][0];
        for (int i = tid; i < NPART*3; i += 256) {
            float v = xs[b*(NPART*3) + i];
            x0f[i] = v; xf[i] = v; dxf[i] = 0.f;
        }
    }
    for (int idx = tid; idx < NPART*HID; idx += 256) {
        int n = idx >> 6, j = idx & 63;
        float acc = emb_b[j] + tb * emb_w[8*HID + j];
        #pragma unroll
        for (int k = 0; k < 8; ++k) acc += h_init[n*8 + k] * emb_w[k*HID + j];
        hsh[n][j] = acc;
        aggs[n][j] = 0.f;
    }
    for (int e = tid; e < 464; e += 256) {
        int ee = (e < NEDGE) ? e : 0;
        int a = ee / NDEG, r = ee - a*NDEG;
        int bb = r + (r >= a ? 1 : 0);
        srcT[e] = (unsigned char)a;
        dstT[e] = (unsigned char)bb;
    }
    __syncthreads();

    for (int L = 0; L < NLAYERS; ++L) {
        // ===== phase 1: stage edge weights (bf16) + vectors; Hr/Hc GEMV from global =====
        stage_wt_bf16s(edge_w2  + L*HID*HID, wbuf,        tid);
        stage_wt_bf16s(coord_w1 + L*HID*HID, wbuf + 8192, tid);
        if (tid < HID) {
            const float* w1 = edge_w1 + L*130*HID;
            vrad[tid] = w1[128*HID + tid];
            vea [tid] = w1[129*HID + tid];
            vb2 [tid] = edge_b2[L*HID + tid];
            vcb1[tid] = coord_b1[L*HID + tid];
            vcw2[tid] = coord_w2[L*HID + tid];
            vbn1[tid] = node_b1[L*HID + tid];
            vbn2[tid] = node_b2[L*HID + tid];
        }
        {
            const float* w1 = edge_w1 + L*130*HID;
            const int j = tid & 63;
            const int nb = tid >> 6;
            float accr[6], accc[6];
            int nsafe[6];
            const float b1v = edge_b1[L*HID + j];
            #pragma unroll
            for (int m = 0; m < 6; ++m) {
                accr[m] = b1v; accc[m] = 0.f;
                int n = nb + m*4;
                nsafe[m] = (n < NPART) ? n : 0;
            }
            #pragma unroll 4
            for (int k = 0; k < HID; ++k) {
                float wr = w1[k*HID + j];
                float wc = w1[(HID + k)*HID + j];
                #pragma unroll
                for (int m = 0; m < 6; ++m) {
                    float hv = hsh[nsafe[m]][k];
                    accr[m] += hv * wr;
                    accc[m] += hv * wc;
                }
            }
            #pragma unroll
            for (int m = 0; m < 6; ++m) {
                int n = nb + m*4;
                if (n < NPART) { Hr[n][j] = accr[m]; Hc[n][j] = accc[m]; }
            }
        }
        __syncthreads();

        // ===== phase 2: edge strips, per-wave, NO barriers =====
        {
            // hoist strip-invariant B-fragments into registers (64 VGPR)
            bf16x8 BW[2][4][2];
            #pragma unroll
            for (int g = 0; g < 2; ++g) {
                #pragma unroll
                for (int nt = 0; nt < 4; ++nt) {
                    int j = nt*16 + j0;
                    const char* rp = wbuf + g*8192 + j*128;
                    int sw = (j & 7) << 4;
                    #pragma unroll
                    for (int c = 0; c < 2; ++c)
                        BW[g][nt][c] = *(const bf16x8*)(rp + ((c*64 + kg*16) ^ sw));
                }
            }

            for (int s = w; s < NSTRIP; s += 4) {
                const int e0 = s * 16;
                const int ecnt = (NEDGE - e0 < 16) ? (NEDGE - e0) : 16;
                int eg = e0 + j0; if (eg >= NEDGE) eg = NEDGE - 1;
                const int a  = srcT[eg];
                const int bb = dstT[eg];
                // geometry (computed redundantly by all 4 kg-groups)
                float d0 = xl[a][0] - xl[bb][0];
                float d1 = xl[a][1] - xl[bb][1];
                float d2 = xl[a][2] - xl[bb][2];
                float rad = d0*d0 + d1*d1 + d2*d2;
                float inv = rsqrtf(rad + 1e-8f);
                float f0 = d0*inv, f1 = d1*inv, f2 = d2*inv;
                float g0 = x0l[a][0] - x0l[bb][0];
                float g1 = x0l[a][1] - x0l[bb][1];
                float g2 = x0l[a][2] - x0l[bb][2];
                float eav = g0*g0 + g1*g1 + g2*g2;
                if (l < 16) scal_sw[w][l] = 0.f;

                // m1 A-fragments in registers
                bf16x8 Ah[2], Al[2];
                {
                    const float* hrp = &Hr[a][0];
                    const float* hcp = &Hc[bb][0];
                    #pragma unroll
                    for (int c = 0; c < 2; ++c) {
                        const int k0 = c*32 + kg*8;
                        float4 ra = *(const float4*)(hrp + k0);
                        float4 rb = *(const float4*)(hrp + k0 + 4);
                        float4 ca = *(const float4*)(hcp + k0);
                        float4 cb = *(const float4*)(hcp + k0 + 4);
                        float4 va = *(const float4*)(vrad + k0);
                        float4 vb = *(const float4*)(vrad + k0 + 4);
                        float4 ua = *(const float4*)(vea + k0);
                        float4 ub = *(const float4*)(vea + k0 + 4);
                        float4 t0, t1;
                        t0.x = silu_f(ra.x + ca.x + rad*va.x + eav*ua.x);
                        t0.y = silu_f(ra.y + ca.y + rad*va.y + eav*ua.y);
                        t0.z = silu_f(ra.z + ca.z + rad*va.z + eav*ua.z);
                        t0.w = silu_f(ra.w + ca.w + rad*va.w + eav*ua.w);
                        t1.x = silu_f(rb.x + cb.x + rad*vb.x + eav*ub.x);
                        t1.y = silu_f(rb.y + cb.y + rad*vb.y + eav*ub.y);
                        t1.z = silu_f(rb.z + cb.z + rad*vb.z + eav*ub.z);
                        t1.w = silu_f(rb.w + cb.w + rad*vb.w + eav*ub.w);
                        split8(t0, t1, Ah[c], Al[c]);
                    }
                }
                // GEMM1: m = m1 @ W2
                f32x4 acc[4];
                #pragma unroll
                for (int nt = 0; nt < 4; ++nt) {
                    f32x4 z = {0.f, 0.f, 0.f, 0.f};
                    z = __builtin_amdgcn_mfma_f32_16x16x32_bf16(Ah[0], BW[0][nt][0], z, 0, 0, 0);
                    z = __builtin_amdgcn_mfma_f32_16x16x32_bf16(Al[0], BW[0][nt][0], z, 0, 0, 0);
                    z = __builtin_amdgcn_mfma_f32_16x16x32_bf16(Ah[1], BW[0][nt][1], z, 0, 0, 0);
                    z = __builtin_amdgcn_mfma_f32_16x16x32_bf16(Al[1], BW[0][nt][1], z, 0, 0, 0);
                    acc[nt] = z;
                }
                // epilogue 1: silu+bias, write m (wave-private), agg atomics
                int ab[4], emask[4];
                #pragma unroll
                for (int r = 0; r < 4; ++r) {
                    int e2 = kg*4 + r;
                    int eg2 = e0 + e2; if (eg2 >= NEDGE) eg2 = NEDGE - 1;
                    ab[r] = (int)srcT[eg2] * NS;
                    emask[r] = (e2 < ecnt);
                }
                #pragma unroll
                for (int nt = 0; nt < 4; ++nt) {
                    int j = nt*16 + j0;
                    float bv = vb2[j];
                    #pragma unroll
                    for (int r = 0; r < 4; ++r) {
                        float mv = silu_f(acc[nt][r] + bv);
                        mw[(kg*4 + r)*NS + j] = mv;
                        if (emask[r]) atomicAdd(&aggsF[ab[r] + j], mv);
                    }
                }
                // GEMM2 A-fragments from wave-private m (same-wave lgkm ordering only)
                bf16x8 A2h[2], A2l[2];
                {
                    const float* arp = mw + j0*NS;
                    #pragma unroll
                    for (int c = 0; c < 2; ++c) {
                        const int k0 = c*32 + kg*8;
                        float4 q0 = *(const float4*)(arp + k0);
                        float4 q1 = *(const float4*)(arp + k0 + 4);
                        split8(q0, q1, A2h[c], A2l[c]);
                    }
                }
                // GEMM2: c1 = m @ Wc1
                f32x4 acc2[4];
                #pragma unroll
                for (int nt = 0; nt < 4; ++nt) {
                    f32x4 z = {0.f, 0.f, 0.f, 0.f};
                    z = __builtin_amdgcn_mfma_f32_16x16x32_bf16(A2h[0], BW[1][nt][0], z, 0, 0, 0);
                    z = __builtin_amdgcn_mfma_f32_16x16x32_bf16(A2l[0], BW[1][nt][0], z, 0, 0, 0);
                    z = __builtin_amdgcn_mfma_f32_16x16x32_bf16(A2h[1], BW[1][nt][1], z, 0, 0, 0);
                    z = __builtin_amdgcn_mfma_f32_16x16x32_bf16(A2l[1], BW[1][nt][1], z, 0, 0, 0);
                    acc2[nt] = z;
                }
                // epilogue 2: scal partials -> wave-private LDS atomics
                float pr[4] = {0.f, 0.f, 0.f, 0.f};
                #pragma unroll
                for (int nt = 0; nt < 4; ++nt) {
                    int j = nt*16 + j0;
                    float cb = vcb1[j], cw = vcw2[j];
                    #pragma unroll
                    for (int r = 0; r < 4; ++r)
                        pr[r] += silu_f(acc2[nt][r] + cb) * cw;
                }
                #pragma unroll
                for (int r = 0; r < 4; ++r)
                    atomicAdd(&scal_sw[w][kg*4 + r], pr[r]);
                // dx atomics (lanes 0..15, their own dif registers)
                if (l < 16 && l < ecnt) {
                    float sc = scal_sw[w][l];
                    atomicAdd(&dxl[a][0], f0 * sc);
                    atomicAdd(&dxl[a][1], f1 * sc);
                    atomicAdd(&dxl[a][2], f2 * sc);
                }
            }
        }
        __syncthreads();

        // ===== x update (+ node weight staging if more node work) =====
        if (tid < NPART*3) {
            int n = tid / 3, d = tid - n*3;
            xl[n][d] += dxl[n][d];
            dxl[n][d] = 0.f;
        }
        if (L < NLAYERS - 1) {
            float* wf = (float*)wbuf;
            for (int idx = tid; idx < 2*HID*HID; idx += 256)
                wf[idx] = node_w1[L*2*HID*HID + idx];
            for (int idx = tid; idx < HID*HID; idx += 256)
                mwav[idx] = node_w2[L*HID*HID + idx];
            __syncthreads();
            // hn = silu([h, agg] @ Wn1 + bn1) -> Hr region
            float* hnp = &Hr[0][0];
            const float* wff = (const float*)wbuf;
            for (int idx = tid; idx < NPART*HID; idx += 256) {
                int n = idx >> 6, j = idx & 63;
                float acc = vbn1[j];
                #pragma unroll 8
                for (int k = 0; k < HID; ++k)
                    acc += hsh[n][k] * wff[k*64 + j] + aggs[n][k] * wff[(64 + k)*64 + j];
                hnp[n*NS + j] = silu_f(acc);
            }
            __syncthreads();
            // h += hn @ Wn2 + bn2 ; zero aggs
            for (int idx = tid; idx < NPART*HID; idx += 256) {
                int n = idx >> 6, j = idx & 63;
                float acc = vbn2[j];
                #pragma unroll 8
                for (int k = 0; k < HID; ++k) acc += hnp[n*NS + k] * mwav[k*64 + j];
                hsh[n][j] += acc;
                aggs[n][j] = 0.f;
            }
            __syncthreads();
        } else {
            __syncthreads();
        }
    }

    // ---- vel = (x - x0) - mean ----
    if (tid < 3) {
        float s = 0.f;
        #pragma unroll
        for (int n = 0; n < NPART; ++n) s += xl[n][tid] - x0l[n][tid];
        meanv[tid] = s / (float)NPART;
    }
    __syncthreads();
    if (tid < NPART*3) {
        int n = tid / 3, d = tid - n*3;
        out[b*(NPART*3) + tid] = (xl[n][d] - x0l[n][d]) - meanv[d];
    }
}

extern "C" void kernel_launch(void* const* d_in, const int* in_sizes, int n_in,
                              void* d_out, int out_size, void* d_ws, size_t ws_size,
                              hipStream_t stream) {
    const float* t_in     = (const float*)d_in[0];
    const float* xs       = (const float*)d_in[1];
    const float* h_init   = (const float*)d_in[2];
    const float* emb_w    = (const float*)d_in[3];
    const float* emb_b    = (const float*)d_in[4];
    const float* edge_w1  = (const float*)d_in[7];
    const float* edge_b1  = (const float*)d_in[8];
    const float* edge_w2  = (const float*)d_in[9];
    const float* edge_b2  = (const float*)d_in[10];
    const float* node_w1  = (const float*)d_in[11];
    const float* node_b1  = (const float*)d_in[12];
    const float* node_w2  = (const float*)d_in[13];
    const float* node_b2  = (const float*)d_in[14];
    const float* coord_w1 = (const float*)d_in[15];
    const float* coord_b1 = (const float*)d_in[16];
    const float* coord_w2 = (const float*)d_in[17];
    float* outp = (float*)d_out;

    const int Bn = in_sizes[0];
    egnn_fused<<<Bn, 256, 0, stream>>>(
        t_in, xs, h_init, emb_w, emb_b,
        edge_w1, edge_b1, edge_w2, edge_b2,
        node_w1, node_b1, node_w2, node_b2,
        coord_w1, coord_b1, coord_w2, outp);
}